// Round 1
// baseline (1697.845 us; speedup 1.0000x reference)
//
#include <hip/hip_runtime.h>
#include <math.h>

#define NROWS 131072
#define DDIM  512
#define BB    32
#define SS    128
#define KK    8

// ---------------------------------------------------------------------------
// q[b][d] = mean_s query[b][s][d]
__global__ __launch_bounds__(256) void k_qmean(const float* __restrict__ query,
                                               float* __restrict__ q) {
  int idx = blockIdx.x * 256 + threadIdx.x;        // 16384 = 32*512
  int b = idx >> 9, d = idx & 511;
  const float* p = query + (size_t)b * SS * DDIM + d;
  float s = 0.f;
  #pragma unroll 8
  for (int i = 0; i < SS; ++i) s += p[(size_t)i * DDIM];
  q[idx] = s * (1.0f / 128.0f);
}

// ---------------------------------------------------------------------------
// new_mem[n][d] = base[n][d] + sum_r A[n][r]*B[r][d]
// lane owns column group c (d = 4c..4c+3); B column slice held in 64 VGPRs.
// Row index is wave-uniform -> A reads become s_loads.
__global__ __launch_bounds__(256) void k_mem(const float* __restrict__ base,
                                             const float* __restrict__ A,
                                             const float* __restrict__ Bm,
                                             float* __restrict__ newmem) {
  int gt = blockIdx.x * 256 + threadIdx.x;
  int c = gt & 127;            // column group, d = 4c..4c+3
  int stream = gt >> 7;        // 0..2047, 64 rows each
  int row0 = stream * 64;
  int srow0 = __builtin_amdgcn_readfirstlane(row0);   // wave-uniform

  float4 Breg[16];
  #pragma unroll
  for (int r = 0; r < 16; ++r)
    Breg[r] = *(const float4*)(Bm + r * DDIM + 4 * c);

  #pragma unroll 4
  for (int i = 0; i < 64; ++i) {
    int n = row0 + i;
    const float* Ar = A + (size_t)(srow0 + i) * 16;
    float4 acc = *(const float4*)(base + (size_t)n * DDIM + 4 * c);
    #pragma unroll
    for (int r = 0; r < 16; ++r) {
      float a = Ar[r];
      acc.x += a * Breg[r].x; acc.y += a * Breg[r].y;
      acc.z += a * Breg[r].z; acc.w += a * Breg[r].w;
    }
    *(float4*)(newmem + (size_t)n * DDIM + 4 * c) = acc;
  }
}

// ---------------------------------------------------------------------------
// scores[b][n] = sum_d q[b][d] * mem[n][d]; lane owns 2 rows, 64 accumulators.
// q addresses are wave-uniform -> s_load + v_fmac with SGPR operand.
__global__ __launch_bounds__(256) void k_scores(const float* __restrict__ mem,
                                                const float* __restrict__ q,
                                                float* __restrict__ scores) {
  int t = threadIdx.x;
  int r0 = blockIdx.x * 512 + t;
  int r1 = r0 + 256;
  float acc0[32], acc1[32];
  #pragma unroll
  for (int b = 0; b < 32; ++b) { acc0[b] = 0.f; acc1[b] = 0.f; }
  const float* m0 = mem + (size_t)r0 * DDIM;
  const float* m1 = mem + (size_t)r1 * DDIM;
  #pragma unroll 4
  for (int d4 = 0; d4 < 128; ++d4) {
    float4 v0 = *(const float4*)(m0 + 4 * d4);
    float4 v1 = *(const float4*)(m1 + 4 * d4);
    #pragma unroll
    for (int b = 0; b < 32; ++b) {
      float4 qv = *(const float4*)(q + b * DDIM + 4 * d4);  // uniform
      acc0[b] += qv.x*v0.x + qv.y*v0.y + qv.z*v0.z + qv.w*v0.w;
      acc1[b] += qv.x*v1.x + qv.y*v1.y + qv.z*v1.z + qv.w*v1.w;
    }
  }
  #pragma unroll
  for (int b = 0; b < 32; ++b) {
    scores[(size_t)b * NROWS + r0] = acc0[b];
    scores[(size_t)b * NROWS + r1] = acc1[b];
  }
}

// ---------------------------------------------------------------------------
// top-k helpers: descending by score, ties -> lower index (matches lax.top_k)
__device__ __forceinline__ void insert8(float (&v)[8], int (&ix)[8], float x, int i) {
  bool better = (x > v[7]) || (x == v[7] && i < ix[7]);
  if (!better) return;
  v[7] = x; ix[7] = i;
  #pragma unroll
  for (int u = 7; u > 0; --u) {
    bool sw = (v[u] > v[u-1]) || (v[u] == v[u-1] && ix[u] < ix[u-1]);
    if (sw) {
      float tv = v[u]; v[u] = v[u-1]; v[u-1] = tv;
      int ti = ix[u]; ix[u] = ix[u-1]; ix[u-1] = ti;
    }
  }
}

__global__ __launch_bounds__(256) void k_topk(const float* __restrict__ scores,
                                              int* __restrict__ topidx) {
  __shared__ float lval[256][8]; __shared__ int lidx[256][8];
  __shared__ float mval[64][8];  __shared__ int midx[64][8];
  __shared__ float fval[8][8];   __shared__ int fidx[8][8];
  int b = blockIdx.x, t = threadIdx.x;
  const float* s = scores + (size_t)b * NROWS;

  float v[8]; int ix[8];
  #pragma unroll
  for (int j = 0; j < 8; ++j) { v[j] = -1e30f; ix[j] = 0x7fffffff; }
  for (int i = t; i < NROWS; i += 256) {   // ascending i per thread
    float x = s[i];
    insert8(v, ix, x, i);
  }
  #pragma unroll
  for (int j = 0; j < 8; ++j) { lval[t][j] = v[j]; lidx[t][j] = ix[j]; }
  __syncthreads();

  if (t < 64) {
    float mv[8]; int mi[8];
    #pragma unroll
    for (int j = 0; j < 8; ++j) { mv[j] = -1e30f; mi[j] = 0x7fffffff; }
    for (int u = 0; u < 4; ++u) {
      int src = t * 4 + u;
      #pragma unroll
      for (int e = 0; e < 8; ++e) insert8(mv, mi, lval[src][e], lidx[src][e]);
    }
    #pragma unroll
    for (int j = 0; j < 8; ++j) { mval[t][j] = mv[j]; midx[t][j] = mi[j]; }
  }
  __syncthreads();

  if (t < 8) {
    float mv[8]; int mi[8];
    #pragma unroll
    for (int j = 0; j < 8; ++j) { mv[j] = -1e30f; mi[j] = 0x7fffffff; }
    for (int u = 0; u < 8; ++u) {
      int src = t * 8 + u;
      #pragma unroll
      for (int e = 0; e < 8; ++e) insert8(mv, mi, mval[src][e], midx[src][e]);
    }
    #pragma unroll
    for (int j = 0; j < 8; ++j) { fval[t][j] = mv[j]; fidx[t][j] = mi[j]; }
  }
  __syncthreads();

  if (t == 0) {
    float mv[8]; int mi[8];
    #pragma unroll
    for (int j = 0; j < 8; ++j) { mv[j] = -1e30f; mi[j] = 0x7fffffff; }
    for (int u = 0; u < 8; ++u) {
      #pragma unroll
      for (int e = 0; e < 8; ++e) insert8(mv, mi, fval[u][e], fidx[u][e]);
    }
    #pragma unroll
    for (int j = 0; j < 8; ++j) topidx[b * 8 + j] = mi[j];
  }
}

// ---------------------------------------------------------------------------
// retrieved[b][k][:] = mem[topidx[b][k]][:]; x[b][:] = sum_k retrieved
__global__ __launch_bounds__(128) void k_gather(const float* __restrict__ mem,
                                                const int* __restrict__ topidx,
                                                float* __restrict__ retrieved,
                                                float* __restrict__ x) {
  int b = blockIdx.x, t = threadIdx.x;   // t in [0,128): d = 4t..4t+3
  float4 xs = make_float4(0.f, 0.f, 0.f, 0.f);
  #pragma unroll
  for (int k = 0; k < 8; ++k) {
    int row = topidx[b * 8 + k];
    float4 vv = *(const float4*)(mem + (size_t)row * DDIM + 4 * t);
    *(float4*)(retrieved + (size_t)(b * 8 + k) * DDIM + 4 * t) = vv;
    xs.x += vv.x; xs.y += vv.y; xs.z += vv.z; xs.w += vv.w;
  }
  *(float4*)(x + (size_t)b * DDIM + 4 * t) = xs;
}

// ---------------------------------------------------------------------------
// GRU cell with h0 = 0:  gh = b_hh, so w_hh GEMM vanishes.
// r = sig(gx_r + bhh_r), z = sig(gx_z + bhh_z), n = tanh(gx_n + r*bhh_n)
// hidden = (1-z)*n ; also p[b] = sig(hidden . wg_w + wg_b)
__global__ __launch_bounds__(512) void k_gru(const float* __restrict__ x,
                                             const float* __restrict__ wih,
                                             const float* __restrict__ bih,
                                             const float* __restrict__ bhh,
                                             const float* __restrict__ wgw,
                                             const float* __restrict__ wgb,
                                             float* __restrict__ hidden,
                                             float* __restrict__ pws) {
  __shared__ float sx[512];
  __shared__ float sred[8];
  int b = blockIdx.x, t = threadIdx.x;
  sx[t] = x[b * 512 + t];
  __syncthreads();
  const float* wr = wih + (size_t)t * 512;
  const float* wz = wih + (size_t)(512 + t) * 512;
  const float* wn = wih + (size_t)(1024 + t) * 512;
  float gr = 0.f, gz = 0.f, gn = 0.f;
  #pragma unroll 4
  for (int d4 = 0; d4 < 128; ++d4) {
    float4 xv = *(const float4*)(sx + 4 * d4);   // broadcast
    float4 a = *(const float4*)(wr + 4 * d4);
    float4 c = *(const float4*)(wz + 4 * d4);
    float4 e = *(const float4*)(wn + 4 * d4);
    gr += a.x*xv.x + a.y*xv.y + a.z*xv.z + a.w*xv.w;
    gz += c.x*xv.x + c.y*xv.y + c.z*xv.z + c.w*xv.w;
    gn += e.x*xv.x + e.y*xv.y + e.z*xv.z + e.w*xv.w;
  }
  float r = 1.f / (1.f + expf(-(gr + bih[t]        + bhh[t])));
  float z = 1.f / (1.f + expf(-(gz + bih[512 + t]  + bhh[512 + t])));
  float n = tanhf(gn + bih[1024 + t] + r * bhh[1024 + t]);
  float h = (1.f - z) * n;
  hidden[b * 512 + t] = h;

  float pw = h * wgw[t];
  #pragma unroll
  for (int off = 32; off > 0; off >>= 1) pw += __shfl_down(pw, off, 64);
  if ((t & 63) == 0) sred[t >> 6] = pw;
  __syncthreads();
  if (t == 0) {
    float ssum = 0.f;
    #pragma unroll
    for (int j = 0; j < 8; ++j) ssum += sred[j];
    pws[b] = 1.f / (1.f + expf(-(ssum + wgb[0])));
  }
}

// ---------------------------------------------------------------------------
// Sequential-over-batch scatter: new_mem[row] = (1-p)*new_mem[row] + p*q[b]
// One block per 64-d slice; cross-batch row collisions ordered by
// __syncthreads; agent-scope atomics bypass L1 so re-reads see prior writes.
__global__ __launch_bounds__(256) void k_scatter(float* __restrict__ newmem,
                                                 const int* __restrict__ topidx,
                                                 const float* __restrict__ pws,
                                                 const float* __restrict__ q) {
  int t = threadIdx.x;
  int d = blockIdx.x * 64 + (t & 63);    // 8 blocks x 64 d = 512
  int k0 = t >> 6;                       // 0..3
  for (int b = 0; b < 32; ++b) {
    float p = pws[b];
    float qv = q[b * 512 + d];
    #pragma unroll
    for (int kk = 0; kk < 2; ++kk) {
      int k = k0 + kk * 4;
      int row = topidx[b * 8 + k];
      size_t off = (size_t)row * 512 + d;
      float m = __hip_atomic_load(newmem + off, __ATOMIC_RELAXED,
                                  __HIP_MEMORY_SCOPE_AGENT);
      __hip_atomic_store(newmem + off, (1.f - p) * m + p * qv,
                         __ATOMIC_RELAXED, __HIP_MEMORY_SCOPE_AGENT);
    }
    __syncthreads();
  }
}

// ---------------------------------------------------------------------------
extern "C" void kernel_launch(void* const* d_in, const int* in_sizes, int n_in,
                              void* d_out, int out_size, void* d_ws, size_t ws_size,
                              hipStream_t stream) {
  const float* query = (const float*)d_in[0];
  const float* base  = (const float*)d_in[1];
  const float* lA    = (const float*)d_in[2];
  const float* lB    = (const float*)d_in[3];
  const float* wih   = (const float*)d_in[4];
  // d_in[5] = gru_w_hh: unused (h0 == 0)
  const float* bih   = (const float*)d_in[6];
  const float* bhh   = (const float*)d_in[7];
  const float* wgw   = (const float*)d_in[8];
  const float* wgb   = (const float*)d_in[9];

  float* out = (float*)d_out;
  float* retrieved = out;                    // 32*8*512   = 131072
  float* hidden    = out + 131072;           // 32*512     = 16384
  float* newmem    = out + 147456;           // 131072*512 = 67108864

  float* wq  = (float*)d_ws;                 // 16384
  float* wsc = wq + 16384;                   // 32*131072 = 4194304
  float* wx  = wsc + 4194304;                // 16384
  float* wp  = wx + 16384;                   // 32
  int*   wti = (int*)(wp + 32);              // 256

  k_qmean  <<<64,   256, 0, stream>>>(query, wq);
  k_mem    <<<1024, 256, 0, stream>>>(base, lA, lB, newmem);
  k_scores <<<256,  256, 0, stream>>>(newmem, wq, wsc);
  k_topk   <<<32,   256, 0, stream>>>(wsc, wti);
  k_gather <<<32,   128, 0, stream>>>(newmem, wti, retrieved, wx);
  k_gru    <<<32,   512, 0, stream>>>(wx, wih, bih, bhh, wgw, wgb, hidden, wp);
  k_scatter<<<8,    256, 0, stream>>>(newmem, wti, wp, wq);
}

// Round 2
// 1051.061 us; speedup vs baseline: 1.6154x; 1.6154x over previous
//
#include <hip/hip_runtime.h>
#include <math.h>

#define NROWS 131072
#define DDIM  512
#define BB    32
#define SS    128
#define KK    8

// ---------------------------------------------------------------------------
// q[b][d] = mean_s query[b][s][d]
__global__ __launch_bounds__(256) void k_qmean(const float* __restrict__ query,
                                               float* __restrict__ q) {
  int idx = blockIdx.x * 256 + threadIdx.x;        // 16384 = 32*512
  int b = idx >> 9, d = idx & 511;
  const float* p = query + (size_t)b * SS * DDIM + d;
  float s = 0.f;
  #pragma unroll 8
  for (int i = 0; i < SS; ++i) s += p[(size_t)i * DDIM];
  q[idx] = s * (1.0f / 128.0f);
}

// ---------------------------------------------------------------------------
// new_mem[n][d] = base[n][d] + sum_r A[n][r]*B[r][d]
// lane owns column group c (d = 4c..4c+3); B column slice held in 64 VGPRs.
__global__ __launch_bounds__(256) void k_mem(const float* __restrict__ base,
                                             const float* __restrict__ A,
                                             const float* __restrict__ Bm,
                                             float* __restrict__ newmem) {
  int gt = blockIdx.x * 256 + threadIdx.x;
  int c = gt & 127;            // column group, d = 4c..4c+3
  int stream = gt >> 7;        // 0..2047, 64 rows each
  int row0 = stream * 64;
  int srow0 = __builtin_amdgcn_readfirstlane(row0);   // wave-uniform

  float4 Breg[16];
  #pragma unroll
  for (int r = 0; r < 16; ++r)
    Breg[r] = *(const float4*)(Bm + r * DDIM + 4 * c);

  #pragma unroll 4
  for (int i = 0; i < 64; ++i) {
    int n = row0 + i;
    const float* Ar = A + (size_t)(srow0 + i) * 16;
    float4 acc = *(const float4*)(base + (size_t)n * DDIM + 4 * c);
    #pragma unroll
    for (int r = 0; r < 16; ++r) {
      float a = Ar[r];
      acc.x += a * Breg[r].x; acc.y += a * Breg[r].y;
      acc.z += a * Breg[r].z; acc.w += a * Breg[r].w;
    }
    *(float4*)(newmem + (size_t)n * DDIM + 4 * c) = acc;
  }
}

// ---------------------------------------------------------------------------
// scores[b][n] = sum_d q[b][d] * mem[n][d]
// 512 blocks x 256 thr, 1 row/thread; q (64 KB) staged in LDS; per-(b,d4)
// LDS reads are wave-uniform -> broadcast, conflict-free.
__global__ __launch_bounds__(256) void k_scores(const float* __restrict__ mem,
                                                const float* __restrict__ q,
                                                float* __restrict__ scores) {
  __shared__ float4 sq[4096];                 // 32 b * 128 d4 = 64 KB
  int t = threadIdx.x;
  const float4* qg = (const float4*)q;
  #pragma unroll
  for (int u = 0; u < 16; ++u) sq[u * 256 + t] = qg[u * 256 + t];
  __syncthreads();

  int r = blockIdx.x * 256 + t;
  float acc[32];
  #pragma unroll
  for (int b = 0; b < 32; ++b) acc[b] = 0.f;
  const float4* mrow = (const float4*)(mem + (size_t)r * DDIM);
  #pragma unroll 2
  for (int d4 = 0; d4 < 128; ++d4) {
    float4 v = mrow[d4];
    #pragma unroll
    for (int b = 0; b < 32; ++b) {
      float4 qv = sq[b * 128 + d4];           // broadcast
      acc[b] += qv.x*v.x + qv.y*v.y + qv.z*v.z + qv.w*v.w;
    }
  }
  #pragma unroll
  for (int b = 0; b < 32; ++b) scores[(size_t)b * NROWS + r] = acc[b];
}

// ---------------------------------------------------------------------------
// top-k comparator: descending by score, ties -> lower index (lax.top_k)
__device__ __forceinline__ void insert8(float (&v)[8], int (&ix)[8], float x, int i) {
  bool better = (x > v[7]) || (x == v[7] && i < ix[7]);
  if (!better) return;
  v[7] = x; ix[7] = i;
  #pragma unroll
  for (int u = 7; u > 0; --u) {
    bool sw = (v[u] > v[u-1]) || (v[u] == v[u-1] && ix[u] < ix[u-1]);
    if (sw) {
      float tv = v[u]; v[u] = v[u-1]; v[u-1] = tv;
      int ti = ix[u]; ix[u] = ix[u-1]; ix[u-1] = ti;
    }
  }
}

// stage 1: grid (32 b x 16 j); block scans 8192 rows -> 8 candidates
__global__ __launch_bounds__(256) void k_topk1(const float* __restrict__ scores,
                                               float* __restrict__ cval,
                                               int* __restrict__ cidx) {
  __shared__ float lval[256][8]; __shared__ int lidx[256][8];
  __shared__ float mval[32][8];  __shared__ int midx[32][8];
  int b = blockIdx.x >> 4, j = blockIdx.x & 15, t = threadIdx.x;
  const float4* s4 = (const float4*)(scores + (size_t)b * NROWS + j * 8192);

  float v[8]; int ix[8];
  #pragma unroll
  for (int e = 0; e < 8; ++e) { v[e] = -1e30f; ix[e] = 0x7fffffff; }
  #pragma unroll
  for (int i = 0; i < 8; ++i) {
    int f4 = i * 256 + t;                     // float4 index in chunk
    float4 x = s4[f4];
    int n0 = j * 8192 + f4 * 4;
    insert8(v, ix, x.x, n0);
    insert8(v, ix, x.y, n0 + 1);
    insert8(v, ix, x.z, n0 + 2);
    insert8(v, ix, x.w, n0 + 3);
  }
  #pragma unroll
  for (int e = 0; e < 8; ++e) { lval[t][e] = v[e]; lidx[t][e] = ix[e]; }
  __syncthreads();

  if (t < 32) {
    float mv[8]; int mi[8];
    #pragma unroll
    for (int e = 0; e < 8; ++e) { mv[e] = -1e30f; mi[e] = 0x7fffffff; }
    for (int u = 0; u < 8; ++u) {
      int src = t * 8 + u;
      #pragma unroll
      for (int e = 0; e < 8; ++e) insert8(mv, mi, lval[src][e], lidx[src][e]);
    }
    #pragma unroll
    for (int e = 0; e < 8; ++e) { mval[t][e] = mv[e]; midx[t][e] = mi[e]; }
  }
  __syncthreads();

  if (t == 0) {
    float mv[8]; int mi[8];
    #pragma unroll
    for (int e = 0; e < 8; ++e) { mv[e] = -1e30f; mi[e] = 0x7fffffff; }
    for (int u = 0; u < 32; ++u)
      #pragma unroll
      for (int e = 0; e < 8; ++e) insert8(mv, mi, mval[u][e], midx[u][e]);
    #pragma unroll
    for (int e = 0; e < 8; ++e) {
      cval[(b * 16 + j) * 8 + e] = mv[e];
      cidx[(b * 16 + j) * 8 + e] = mi[e];
    }
  }
}

// ---------------------------------------------------------------------------
// stage-2 merge (128 candidates -> top-8) fused with gather:
// retrieved[b][k][:] = mem[topidx[b][k]][:]; x[b][:] = sum_k retrieved
__global__ __launch_bounds__(128) void k_gather(const float* __restrict__ mem,
                                                const float* __restrict__ cval,
                                                const int* __restrict__ cidx,
                                                int* __restrict__ topidx,
                                                float* __restrict__ retrieved,
                                                float* __restrict__ x) {
  __shared__ float scv[128]; __shared__ int sci[128];
  __shared__ int stop[8];
  int b = blockIdx.x, t = threadIdx.x;   // t in [0,128)
  scv[t] = cval[b * 128 + t];
  sci[t] = cidx[b * 128 + t];
  __syncthreads();
  if (t == 0) {
    float mv[8]; int mi[8];
    #pragma unroll
    for (int e = 0; e < 8; ++e) { mv[e] = -1e30f; mi[e] = 0x7fffffff; }
    for (int u = 0; u < 128; ++u) insert8(mv, mi, scv[u], sci[u]);
    #pragma unroll
    for (int e = 0; e < 8; ++e) { stop[e] = mi[e]; topidx[b * 8 + e] = mi[e]; }
  }
  __syncthreads();

  float4 xs = make_float4(0.f, 0.f, 0.f, 0.f);
  #pragma unroll
  for (int k = 0; k < 8; ++k) {
    int row = stop[k];
    float4 vv = *(const float4*)(mem + (size_t)row * DDIM + 4 * t);
    *(float4*)(retrieved + (size_t)(b * 8 + k) * DDIM + 4 * t) = vv;
    xs.x += vv.x; xs.y += vv.y; xs.z += vv.z; xs.w += vv.w;
  }
  *(float4*)(x + (size_t)b * DDIM + 4 * t) = xs;
}

// ---------------------------------------------------------------------------
// GRU cell with h0 = 0:  gh = b_hh, so w_hh GEMM vanishes.
__global__ __launch_bounds__(512) void k_gru(const float* __restrict__ x,
                                             const float* __restrict__ wih,
                                             const float* __restrict__ bih,
                                             const float* __restrict__ bhh,
                                             const float* __restrict__ wgw,
                                             const float* __restrict__ wgb,
                                             float* __restrict__ hidden,
                                             float* __restrict__ pws) {
  __shared__ float sx[512];
  __shared__ float sred[8];
  int b = blockIdx.x, t = threadIdx.x;
  sx[t] = x[b * 512 + t];
  __syncthreads();
  const float* wr = wih + (size_t)t * 512;
  const float* wz = wih + (size_t)(512 + t) * 512;
  const float* wn = wih + (size_t)(1024 + t) * 512;
  float gr = 0.f, gz = 0.f, gn = 0.f;
  #pragma unroll 4
  for (int d4 = 0; d4 < 128; ++d4) {
    float4 xv = *(const float4*)(sx + 4 * d4);   // broadcast
    float4 a = *(const float4*)(wr + 4 * d4);
    float4 c = *(const float4*)(wz + 4 * d4);
    float4 e = *(const float4*)(wn + 4 * d4);
    gr += a.x*xv.x + a.y*xv.y + a.z*xv.z + a.w*xv.w;
    gz += c.x*xv.x + c.y*xv.y + c.z*xv.z + c.w*xv.w;
    gn += e.x*xv.x + e.y*xv.y + e.z*xv.z + e.w*xv.w;
  }
  float r = 1.f / (1.f + expf(-(gr + bih[t]        + bhh[t])));
  float z = 1.f / (1.f + expf(-(gz + bih[512 + t]  + bhh[512 + t])));
  float n = tanhf(gn + bih[1024 + t] + r * bhh[1024 + t]);
  float h = (1.f - z) * n;
  hidden[b * 512 + t] = h;

  float pw = h * wgw[t];
  #pragma unroll
  for (int off = 32; off > 0; off >>= 1) pw += __shfl_down(pw, off, 64);
  if ((t & 63) == 0) sred[t >> 6] = pw;
  __syncthreads();
  if (t == 0) {
    float ssum = 0.f;
    #pragma unroll
    for (int j = 0; j < 8; ++j) ssum += sred[j];
    pws[b] = 1.f / (1.f + expf(-(ssum + wgb[0])));
  }
}

// ---------------------------------------------------------------------------
// Sequential-over-batch scatter: new_mem[row] = (1-p)*new_mem[row] + p*q[b]
__global__ __launch_bounds__(256) void k_scatter(float* __restrict__ newmem,
                                                 const int* __restrict__ topidx,
                                                 const float* __restrict__ pws,
                                                 const float* __restrict__ q) {
  int t = threadIdx.x;
  int d = blockIdx.x * 64 + (t & 63);    // 8 blocks x 64 d = 512
  int k0 = t >> 6;                       // 0..3
  for (int b = 0; b < 32; ++b) {
    float p = pws[b];
    float qv = q[b * 512 + d];
    #pragma unroll
    for (int kk = 0; kk < 2; ++kk) {
      int k = k0 + kk * 4;
      int row = topidx[b * 8 + k];
      size_t off = (size_t)row * 512 + d;
      float m = __hip_atomic_load(newmem + off, __ATOMIC_RELAXED,
                                  __HIP_MEMORY_SCOPE_AGENT);
      __hip_atomic_store(newmem + off, (1.f - p) * m + p * qv,
                         __ATOMIC_RELAXED, __HIP_MEMORY_SCOPE_AGENT);
    }
    __syncthreads();
  }
}

// ---------------------------------------------------------------------------
extern "C" void kernel_launch(void* const* d_in, const int* in_sizes, int n_in,
                              void* d_out, int out_size, void* d_ws, size_t ws_size,
                              hipStream_t stream) {
  const float* query = (const float*)d_in[0];
  const float* base  = (const float*)d_in[1];
  const float* lA    = (const float*)d_in[2];
  const float* lB    = (const float*)d_in[3];
  const float* wih   = (const float*)d_in[4];
  // d_in[5] = gru_w_hh: unused (h0 == 0)
  const float* bih   = (const float*)d_in[6];
  const float* bhh   = (const float*)d_in[7];
  const float* wgw   = (const float*)d_in[8];
  const float* wgb   = (const float*)d_in[9];

  float* out = (float*)d_out;
  float* retrieved = out;                    // 32*8*512   = 131072
  float* hidden    = out + 131072;           // 32*512     = 16384
  float* newmem    = out + 147456;           // 131072*512 = 67108864

  float* wq  = (float*)d_ws;                 // 16384
  float* wsc = wq + 16384;                   // 32*131072 = 4194304
  float* wx  = wsc + 4194304;                // 16384
  float* wp  = wx + 16384;                   // 32
  int*   wti = (int*)(wp + 32);              // 256
  float* wcv = (float*)(wti + 256);          // 32*16*8 = 4096
  int*   wci = (int*)(wcv + 4096);           // 4096

  k_qmean  <<<64,   256, 0, stream>>>(query, wq);
  k_mem    <<<1024, 256, 0, stream>>>(base, lA, lB, newmem);
  k_scores <<<512,  256, 0, stream>>>(newmem, wq, wsc);
  k_topk1  <<<512,  256, 0, stream>>>(wsc, wcv, wci);
  k_gather <<<32,   128, 0, stream>>>(newmem, wcv, wci, wti, retrieved, wx);
  k_gru    <<<32,   512, 0, stream>>>(wx, wih, bih, bhh, wgw, wgb, hidden, wp);
  k_scatter<<<8,    256, 0, stream>>>(newmem, wti, wp, wq);
}